// Round 1
// baseline (3367.418 us; speedup 1.0000x reference)
//
#include <hip/hip_runtime.h>

#define FH 128
#define NEG 0.01f
#define BNEPS 1e-5f

__device__ __forceinline__ float lrelu(float v){ return v >= 0.f ? v : NEG * v; }

// ---------------- CSR build ----------------
__global__ void k_hist(const int* __restrict__ dst, int E, int* __restrict__ cnt){
  int i = blockIdx.x * 256 + threadIdx.x;
  if (i < E) atomicAdd(&cnt[dst[i]], 1);
}

__global__ void k_fill(const int* __restrict__ src, const int* __restrict__ dst, int E,
                       int* __restrict__ cur, int* __restrict__ csr){
  int i = blockIdx.x * 256 + threadIdx.x;
  if (i < E){
    int slot = atomicAdd(&cur[dst[i]], 1);
    csr[slot] = src[i];
  }
}

// chunk = 1024 elems, 256 threads x 4
__global__ void k_chunk_sums(const int* c0, const int* c1, const int* c2, const int* c3,
                             int l0, int l1, int l2, int l3, int* __restrict__ sums){
  int a = blockIdx.y;
  const int* c = a==0?c0 : a==1?c1 : a==2?c2 : c3;
  int len     = a==0?l0 : a==1?l1 : a==2?l2 : l3;
  int base = blockIdx.x * 1024;
  if (base >= len) return;
  int t = threadIdx.x;
  int s = 0;
  #pragma unroll
  for (int u = 0; u < 4; ++u){ int i = base + t*4 + u; if (i < len) s += c[i]; }
  __shared__ int red[256];
  red[t] = s; __syncthreads();
  for (int o = 128; o > 0; o >>= 1){ if (t < o) red[t] += red[t+o]; __syncthreads(); }
  if (t == 0) sums[a*256 + blockIdx.x] = red[0];
}

__global__ void k_scan_sums(int* sums, int n0, int n1, int n2, int n3){
  int a = blockIdx.x;
  int n = a==0?n0 : a==1?n1 : a==2?n2 : n3;
  int t = threadIdx.x;
  __shared__ int shm[256];
  shm[t] = (t < n) ? sums[a*256 + t] : 0;
  __syncthreads();
  for (int o = 1; o < 256; o <<= 1){
    int x = shm[t];
    if (t >= o) x += shm[t-o];
    __syncthreads();
    shm[t] = x;
    __syncthreads();
  }
  sums[a*256 + t] = t ? shm[t-1] : 0;
}

__global__ void k_write_offsets(const int* c0, const int* c1, const int* c2, const int* c3,
                                int* o0, int* o1, int* o2, int* o3,
                                int* u0, int* u1, int* u2, int* u3,
                                int l0, int l1, int l2, int l3,
                                const int* __restrict__ sums){
  int a = blockIdx.y;
  const int* c = a==0?c0 : a==1?c1 : a==2?c2 : c3;
  int* off     = a==0?o0 : a==1?o1 : a==2?o2 : o3;
  int* cur     = a==0?u0 : a==1?u1 : a==2?u2 : u3;
  int len      = a==0?l0 : a==1?l1 : a==2?l2 : l3;
  int base = blockIdx.x * 1024;
  if (base >= len) return;
  int t = threadIdx.x;
  int v[4]; int s = 0;
  #pragma unroll
  for (int u = 0; u < 4; ++u){ int i = base + t*4 + u; v[u] = (i < len) ? c[i] : 0; s += v[u]; }
  __shared__ int shm[256];
  shm[t] = s; __syncthreads();
  for (int o = 1; o < 256; o <<= 1){
    int x = shm[t];
    if (t >= o) x += shm[t-o];
    __syncthreads();
    shm[t] = x;
    __syncthreads();
  }
  int run = (t ? shm[t-1] : 0) + sums[a*256 + blockIdx.x];
  #pragma unroll
  for (int u = 0; u < 4; ++u){
    int i = base + t*4 + u;
    if (i < len){
      off[i] = run; cur[i] = run; run += v[u];
      if (i == len - 1) off[len] = run;
    }
  }
}

// ---------------- weight concat ----------------
// wcat layout: [blk*2+side][384][128], value at [k][c] multiplies A feature k -> out col c.
// side 0 (flow): parts = (sends Wl0, precedes Wl2, 0.5*(Wr0+Wr2)), bias 0.5*(bl0+bl2)
// side 1 (host): parts = (rev Wl1, reaches Wl3, 0.5*(Wr1+Wr3)), bias 0.5*(bl1+bl3)
__global__ void k_prep(const float* __restrict__ Wl, const float* __restrict__ bl,
                       const float* __restrict__ Wr, float* __restrict__ wcat,
                       float* __restrict__ bcat){
  int g = blockIdx.x * 256 + threadIdx.x;
  const int NW = 4 * 384 * 128;
  if (g < NW){
    int which = g / 49152;          // blk*2 + side
    int blk = which >> 1, side = which & 1;
    int idx = g % 49152;
    int k = idx >> 7;               // 0..383
    int c = idx & 127;
    int part = k >> 7, kk = k & 127;
    int tA = side == 0 ? 0 : 1;
    int tB = side == 0 ? 2 : 3;
    float v;
    if (part == 0)      v = 0.5f * Wl[(((blk*4 + tA)*128 + c)*128) + kk];
    else if (part == 1) v = 0.5f * Wl[(((blk*4 + tB)*128 + c)*128) + kk];
    else v = 0.5f * (Wr[(((blk*4 + tA)*128 + c)*128) + kk] + Wr[(((blk*4 + tB)*128 + c)*128) + kk]);
    wcat[which*49152 + k*128 + c] = v;
  } else if (g < NW + 512){
    int i = g - NW;
    int which = i >> 7;
    int blk = which >> 1, side = which & 1;
    int c = i & 127;
    int tA = side == 0 ? 0 : 1;
    int tB = side == 0 ? 2 : 3;
    bcat[which*128 + c] = 0.5f * (bl[(blk*4 + tA)*128 + c] + bl[(blk*4 + tB)*128 + c]);
  }
}

// ---------------- fused gather-mean + GEMM ----------------
// out[row][c] = sum over 3 parts of A_part[row][k] * W[part*128+k][c] + bias[c]
// part0/1: A = mean over CSR edges of lrelu(bn(tab[src])) (bn optional)
// part2:   A = lrelu(bn(tabd[row]))
__global__ __launch_bounds__(256) void k_gemm(
    int M,
    const int* __restrict__ off0, const int* __restrict__ csr0, const float* __restrict__ tab0,
    const float* __restrict__ sc0, const float* __restrict__ sh0,
    const int* __restrict__ off1, const int* __restrict__ csr1, const float* __restrict__ tab1,
    const float* __restrict__ sc1, const float* __restrict__ sh1,
    const float* __restrict__ tabd, const float* __restrict__ scd, const float* __restrict__ shd,
    const float* __restrict__ W, const float* __restrict__ bias,
    float* __restrict__ out)
{
  __shared__ float As[64][132];   // padded: +4 floats -> 2-way-max bank aliasing (free)
  __shared__ float Bs[32][128];
  const int tid = threadIdx.x;
  const int tr = tid >> 4, tc = tid & 15;
  const int row0 = blockIdx.x * 64;
  const int lane = tid & 63;
  const int wave = tid >> 6;
  const int sub = lane >> 5;      // half-wave: 32 lanes x float4 cover a 128-f32 row
  const int li = lane & 31;
  float acc[4][8] = {};

  for (int part = 0; part < 3; ++part){
    __syncthreads();              // previous part's As/Bs reads complete
    const int* off; const int* csr; const float* tab; const float* sc; const float* sh;
    if (part == 0){ off = off0; csr = csr0; tab = tab0; sc = sc0; sh = sh0; }
    else if (part == 1){ off = off1; csr = csr1; tab = tab1; sc = sc1; sh = sh1; }
    else { off = nullptr; csr = nullptr; tab = tabd; sc = scd; sh = shd; }
    const bool bn = (sc != nullptr);
    float4 scv = make_float4(1.f,1.f,1.f,1.f), shv = make_float4(0.f,0.f,0.f,0.f);
    if (bn){ scv = *(const float4*)(sc + 4*li); shv = *(const float4*)(sh + 4*li); }

    // each wave stages 16 rows, two at a time (half-wave per row)
    for (int rr = 0; rr < 8; ++rr){
      int r = (wave << 4) + (rr << 1) + sub;
      int row = row0 + r;
      float4 v = make_float4(0.f,0.f,0.f,0.f);
      if (row < M){
        if (part < 2){
          int s = off[row], e = off[row+1];
          if (bn){
            for (int i = s; i < e; ++i){
              int sn = csr[i];
              float4 x = *(const float4*)(tab + (size_t)sn*FH + 4*li);
              v.x += lrelu(fmaf(x.x, scv.x, shv.x));
              v.y += lrelu(fmaf(x.y, scv.y, shv.y));
              v.z += lrelu(fmaf(x.z, scv.z, shv.z));
              v.w += lrelu(fmaf(x.w, scv.w, shv.w));
            }
          } else {
            for (int i = s; i < e; ++i){
              int sn = csr[i];
              float4 x = *(const float4*)(tab + (size_t)sn*FH + 4*li);
              v.x += x.x; v.y += x.y; v.z += x.z; v.w += x.w;
            }
          }
          int n = e - s;
          float inv = 1.f / (float)(n > 1 ? n : 1);
          v.x *= inv; v.y *= inv; v.z *= inv; v.w *= inv;
        } else {
          float4 x = *(const float4*)(tab + (size_t)row*FH + 4*li);
          if (bn){
            v.x = lrelu(fmaf(x.x, scv.x, shv.x));
            v.y = lrelu(fmaf(x.y, scv.y, shv.y));
            v.z = lrelu(fmaf(x.z, scv.z, shv.z));
            v.w = lrelu(fmaf(x.w, scv.w, shv.w));
          } else v = x;
        }
      }
      *(float4*)&As[r][4*li] = v;
    }
    __syncthreads();

    for (int kc = 0; kc < 4; ++kc){
      if (kc) __syncthreads();    // prior chunk's Bs reads complete
      const float* wsrc = W + (part*128 + kc*32)*128;
      #pragma unroll
      for (int u = 0; u < 4; ++u){
        int idx = (tid + u*256) * 4;
        *(float4*)((float*)Bs + idx) = *(const float4*)(wsrc + idx);
      }
      __syncthreads();
      #pragma unroll 4
      for (int k = 0; k < 32; ++k){
        float av[4];
        #pragma unroll
        for (int j = 0; j < 4; ++j) av[j] = As[tr*4 + j][kc*32 + k];
        float4 b0 = *(const float4*)&Bs[k][tc*8];
        float4 b1 = *(const float4*)&Bs[k][tc*8 + 4];
        #pragma unroll
        for (int j = 0; j < 4; ++j){
          acc[j][0] = fmaf(av[j], b0.x, acc[j][0]);
          acc[j][1] = fmaf(av[j], b0.y, acc[j][1]);
          acc[j][2] = fmaf(av[j], b0.z, acc[j][2]);
          acc[j][3] = fmaf(av[j], b0.w, acc[j][3]);
          acc[j][4] = fmaf(av[j], b1.x, acc[j][4]);
          acc[j][5] = fmaf(av[j], b1.y, acc[j][5]);
          acc[j][6] = fmaf(av[j], b1.z, acc[j][6]);
          acc[j][7] = fmaf(av[j], b1.w, acc[j][7]);
        }
      }
    }
  }

  float4 bi0 = *(const float4*)&bias[tc*8];
  float4 bi1 = *(const float4*)&bias[tc*8 + 4];
  #pragma unroll
  for (int j = 0; j < 4; ++j){
    int row = row0 + tr*4 + j;
    if (row < M){
      float4 o0 = make_float4(acc[j][0]+bi0.x, acc[j][1]+bi0.y, acc[j][2]+bi0.z, acc[j][3]+bi0.w);
      float4 o1 = make_float4(acc[j][4]+bi1.x, acc[j][5]+bi1.y, acc[j][6]+bi1.z, acc[j][7]+bi1.w);
      *(float4*)(out + (size_t)row*FH + tc*8) = o0;
      *(float4*)(out + (size_t)row*FH + tc*8 + 4) = o1;
    }
  }
}

// ---------------- BN ----------------
__global__ void k_bn_stats(const float* __restrict__ x, int M,
                           float* __restrict__ gsum, float* __restrict__ gsq){
  int t = threadIdx.x;
  int f = t & 127;
  int half = t >> 7;
  float s = 0.f, q = 0.f;
  for (int row = blockIdx.x*2 + half; row < M; row += gridDim.x*2){
    float v = x[(size_t)row*FH + f];
    s += v; q += v*v;
  }
  __shared__ float red[256];
  red[t] = s; __syncthreads();
  if (t < 128) atomicAdd(&gsum[t], red[t] + red[t+128]);
  __syncthreads();
  red[t] = q; __syncthreads();
  if (t < 128) atomicAdd(&gsq[t], red[t] + red[t+128]);
}

__global__ void k_bn_finalize(const float* __restrict__ sF, const float* __restrict__ qF, float invMF,
                              const float* __restrict__ sH, const float* __restrict__ qH, float invMH,
                              const float* __restrict__ gamma, const float* __restrict__ beta,
                              float* scF, float* shF, float* scH, float* shH){
  int t = threadIdx.x;
  if (t < 128){
    float mu = sF[t] * invMF;
    float var = qF[t] * invMF - mu*mu;
    float s = gamma[t] * rsqrtf(var + BNEPS);
    scF[t] = s; shF[t] = beta[t] - mu*s;
  } else {
    int f = t - 128;
    float mu = sH[f] * invMH;
    float var = qH[f] * invMH - mu*mu;
    float s = gamma[f] * rsqrtf(var + BNEPS);
    scH[f] = s; shH[f] = beta[f] - mu*s;
  }
}

__global__ void k_apply(float* __restrict__ x, int n4,
                        const float* __restrict__ sc, const float* __restrict__ shf){
  int g = blockIdx.x * blockDim.x + threadIdx.x;
  int stride = gridDim.x * blockDim.x;
  for (int i = g; i < n4; i += stride){
    float4 v = ((const float4*)x)[i];
    int f = (i*4) & 127;
    float4 s = *(const float4*)(sc + f);
    float4 b = *(const float4*)(shf + f);
    v.x = lrelu(fmaf(v.x, s.x, b.x));
    v.y = lrelu(fmaf(v.y, s.y, b.y));
    v.z = lrelu(fmaf(v.z, s.z, b.z));
    v.w = lrelu(fmaf(v.w, s.w, b.w));
    ((float4*)x)[i] = v;
  }
}

// ---------------- launch ----------------
extern "C" void kernel_launch(void* const* d_in, const int* in_sizes, int n_in,
                              void* d_out, int out_size, void* d_ws, size_t ws_size,
                              hipStream_t stream) {
  const float* x_host = (const float*)d_in[0];
  const float* x_flow = (const float*)d_in[1];
  const int* ei_s  = (const int*)d_in[2];
  const int* ei_rv = (const int*)d_in[3];
  const int* ei_p  = (const int*)d_in[4];
  const int* ei_rc = (const int*)d_in[5];
  const float* Wl    = (const float*)d_in[6];
  const float* bl    = (const float*)d_in[7];
  const float* Wr    = (const float*)d_in[8];
  const float* gamma = (const float*)d_in[9];
  const float* beta  = (const float*)d_in[10];

  const int NH = in_sizes[0] / FH;   // 50000
  const int NF = in_sizes[1] / FH;   // 200000
  const int Es  = in_sizes[2] / 2;
  const int Erv = in_sizes[3] / 2;
  const int Ep  = in_sizes[4] / 2;
  const int Erc = in_sizes[5] / 2;

  float* out_h = (float*)d_out;
  float* out_f = (float*)d_out + (size_t)NH * FH;

  char* p = (char*)d_ws;
  auto alloc = [&](size_t bytes) -> void* {
    void* r = (void*)p;
    p += (bytes + 255) & ~(size_t)255;
    return r;
  };
  float* f_raw0 = (float*)alloc((size_t)NF * FH * 4);
  float* h_raw0 = (float*)alloc((size_t)NH * FH * 4);
  float* wcat   = (float*)alloc((size_t)4 * 49152 * 4);
  float* bcat   = (float*)alloc(512 * 4);
  float* stats  = (float*)alloc(1024 * 4);   // per blk*512: sumF,sqF,sumH,sqH (128 each)
  float* ssbuf  = (float*)alloc(1024 * 4);   // per blk*512: scF,shF,scH,shH
  int* cnt_s = (int*)alloc((size_t)NF * 4);
  int* cnt_p = (int*)alloc((size_t)NF * 4);
  int* cnt_r = (int*)alloc((size_t)NH * 4);
  int* cnt_q = (int*)alloc((size_t)NH * 4);
  int* off_s = (int*)alloc((size_t)(NF+1) * 4);
  int* off_p = (int*)alloc((size_t)(NF+1) * 4);
  int* off_r = (int*)alloc((size_t)(NH+1) * 4);
  int* off_q = (int*)alloc((size_t)(NH+1) * 4);
  int* cur_s = (int*)alloc((size_t)NF * 4);
  int* cur_p = (int*)alloc((size_t)NF * 4);
  int* cur_r = (int*)alloc((size_t)NH * 4);
  int* cur_q = (int*)alloc((size_t)NH * 4);
  int* csr_s = (int*)alloc((size_t)Es * 4);
  int* csr_p = (int*)alloc((size_t)Ep * 4);
  int* csr_r = (int*)alloc((size_t)Erv * 4);
  int* csr_q = (int*)alloc((size_t)Erc * 4);
  int* ssum  = (int*)alloc(1024 * 4);

  // zero counts + stats (everything else fully written before read)
  size_t cnt_bytes = (char*)cnt_q + (size_t)NH*4 - (char*)cnt_s;
  hipMemsetAsync(cnt_s, 0, cnt_bytes, stream);
  hipMemsetAsync(stats, 0, 1024 * 4, stream);

  k_prep<<<(4*384*128 + 512 + 255)/256, 256, 0, stream>>>(Wl, bl, Wr, wcat, bcat);

  k_hist<<<(Es +255)/256, 256, 0, stream>>>(ei_s  + Es,  Es,  cnt_s);
  k_hist<<<(Ep +255)/256, 256, 0, stream>>>(ei_p  + Ep,  Ep,  cnt_p);
  k_hist<<<(Erv+255)/256, 256, 0, stream>>>(ei_rv + Erv, Erv, cnt_r);
  k_hist<<<(Erc+255)/256, 256, 0, stream>>>(ei_rc + Erc, Erc, cnt_q);

  int nchF = (NF + 1023) / 1024;   // 196
  int nchH = (NH + 1023) / 1024;   // 49
  dim3 gscan(nchF, 4);
  k_chunk_sums<<<gscan, 256, 0, stream>>>(cnt_s, cnt_p, cnt_r, cnt_q, NF, NF, NH, NH, ssum);
  k_scan_sums<<<4, 256, 0, stream>>>(ssum, nchF, nchF, nchH, nchH);
  k_write_offsets<<<gscan, 256, 0, stream>>>(cnt_s, cnt_p, cnt_r, cnt_q,
                                             off_s, off_p, off_r, off_q,
                                             cur_s, cur_p, cur_r, cur_q,
                                             NF, NF, NH, NH, ssum);

  k_fill<<<(Es +255)/256, 256, 0, stream>>>(ei_s,  ei_s  + Es,  Es,  cur_s, csr_s);
  k_fill<<<(Ep +255)/256, 256, 0, stream>>>(ei_p,  ei_p  + Ep,  Ep,  cur_p, csr_p);
  k_fill<<<(Erv+255)/256, 256, 0, stream>>>(ei_rv, ei_rv + Erv, Erv, cur_r, csr_r);
  k_fill<<<(Erc+255)/256, 256, 0, stream>>>(ei_rc, ei_rc + Erc, Erc, cur_q, csr_q);

  int gF = (NF + 63) / 64;   // 3125
  int gH = (NH + 63) / 64;   // 782

  for (int blk = 0; blk < 2; ++blk){
    const float* fcur = blk ? f_raw0 : x_flow;
    const float* hcur = blk ? h_raw0 : x_host;
    // BN scale/shift of the PREVIOUS block (producing fcur/hcur); null for raw inputs
    const float* scF = blk ? ssbuf + 0   : nullptr;
    const float* shF = blk ? ssbuf + 128 : nullptr;
    const float* scH = blk ? ssbuf + 256 : nullptr;
    const float* shH = blk ? ssbuf + 384 : nullptr;
    float* outF = blk ? out_f : f_raw0;
    float* outH = blk ? out_h : h_raw0;
    const float* wf = wcat + (blk*2 + 0) * 49152;
    const float* wh = wcat + (blk*2 + 1) * 49152;
    const float* bf = bcat + (blk*2 + 0) * 128;
    const float* bh = bcat + (blk*2 + 1) * 128;

    // flow-side: part0 sends (src=host), part1 precedes (src=flow), dst=flow
    k_gemm<<<gF, 256, 0, stream>>>(NF,
        off_s, csr_s, hcur, scH, shH,
        off_p, csr_p, fcur, scF, shF,
        fcur, scF, shF,
        wf, bf, outF);
    // host-side: part0 rev_sends (src=flow), part1 reaches (src=flow), dst=host
    k_gemm<<<gH, 256, 0, stream>>>(NH,
        off_r, csr_r, fcur, scF, shF,
        off_q, csr_q, fcur, scF, shF,
        hcur, scH, shH,
        wh, bh, outH);

    float* st = stats + blk * 512;
    k_bn_stats<<<512, 256, 0, stream>>>(outF, NF, st + 0,   st + 128);
    k_bn_stats<<<512, 256, 0, stream>>>(outH, NH, st + 256, st + 384);
    float* ss = ssbuf + blk * 512;
    k_bn_finalize<<<1, 256, 0, stream>>>(st + 0, st + 128, 1.f/(float)NF,
                                         st + 256, st + 384, 1.f/(float)NH,
                                         gamma + blk*128, beta + blk*128,
                                         ss + 0, ss + 128, ss + 256, ss + 384);
  }

  // final BN+lrelu applied in place on d_out (block-1 raw outputs)
  k_apply<<<2048, 256, 0, stream>>>(out_f, NF * FH / 4, ssbuf + 512 + 0,   ssbuf + 512 + 128);
  k_apply<<<2048, 256, 0, stream>>>(out_h, NH * FH / 4, ssbuf + 512 + 256, ssbuf + 512 + 384);
}

// Round 2
// 2358.815 us; speedup vs baseline: 1.4276x; 1.4276x over previous
//
#include <hip/hip_runtime.h>

#define FH 128
#define NEG 0.01f
#define BNEPS 1e-5f

__device__ __forceinline__ float lrelu(float v){ return v >= 0.f ? v : NEG * v; }

// ---------------- CSR build ----------------
__global__ void k_hist(const int* __restrict__ dst, int E, int* __restrict__ cnt){
  int i = blockIdx.x * 256 + threadIdx.x;
  if (i < E) atomicAdd(&cnt[dst[i]], 1);
}

__global__ void k_fill(const int* __restrict__ src, const int* __restrict__ dst, int E,
                       int* __restrict__ cur, int* __restrict__ csr){
  int i = blockIdx.x * 256 + threadIdx.x;
  if (i < E){
    int slot = atomicAdd(&cur[dst[i]], 1);
    csr[slot] = src[i];
  }
}

// chunk = 1024 elems, 256 threads x 4
__global__ void k_chunk_sums(const int* c0, const int* c1, const int* c2, const int* c3,
                             int l0, int l1, int l2, int l3, int* __restrict__ sums){
  int a = blockIdx.y;
  const int* c = a==0?c0 : a==1?c1 : a==2?c2 : c3;
  int len     = a==0?l0 : a==1?l1 : a==2?l2 : l3;
  int base = blockIdx.x * 1024;
  if (base >= len) return;
  int t = threadIdx.x;
  int s = 0;
  #pragma unroll
  for (int u = 0; u < 4; ++u){ int i = base + t*4 + u; if (i < len) s += c[i]; }
  __shared__ int red[256];
  red[t] = s; __syncthreads();
  for (int o = 128; o > 0; o >>= 1){ if (t < o) red[t] += red[t+o]; __syncthreads(); }
  if (t == 0) sums[a*256 + blockIdx.x] = red[0];
}

__global__ void k_scan_sums(int* sums, int n0, int n1, int n2, int n3){
  int a = blockIdx.x;
  int n = a==0?n0 : a==1?n1 : a==2?n2 : n3;
  int t = threadIdx.x;
  __shared__ int shm[256];
  shm[t] = (t < n) ? sums[a*256 + t] : 0;
  __syncthreads();
  for (int o = 1; o < 256; o <<= 1){
    int x = shm[t];
    if (t >= o) x += shm[t-o];
    __syncthreads();
    shm[t] = x;
    __syncthreads();
  }
  sums[a*256 + t] = t ? shm[t-1] : 0;
}

__global__ void k_write_offsets(const int* c0, const int* c1, const int* c2, const int* c3,
                                int* o0, int* o1, int* o2, int* o3,
                                int* u0, int* u1, int* u2, int* u3,
                                int l0, int l1, int l2, int l3,
                                const int* __restrict__ sums){
  int a = blockIdx.y;
  const int* c = a==0?c0 : a==1?c1 : a==2?c2 : c3;
  int* off     = a==0?o0 : a==1?o1 : a==2?o2 : o3;
  int* cur     = a==0?u0 : a==1?u1 : a==2?u2 : u3;
  int len      = a==0?l0 : a==1?l1 : a==2?l2 : l3;
  int base = blockIdx.x * 1024;
  if (base >= len) return;
  int t = threadIdx.x;
  int v[4]; int s = 0;
  #pragma unroll
  for (int u = 0; u < 4; ++u){ int i = base + t*4 + u; v[u] = (i < len) ? c[i] : 0; s += v[u]; }
  __shared__ int shm[256];
  shm[t] = s; __syncthreads();
  for (int o = 1; o < 256; o <<= 1){
    int x = shm[t];
    if (t >= o) x += shm[t-o];
    __syncthreads();
    shm[t] = x;
    __syncthreads();
  }
  int run = (t ? shm[t-1] : 0) + sums[a*256 + blockIdx.x];
  #pragma unroll
  for (int u = 0; u < 4; ++u){
    int i = base + t*4 + u;
    if (i < len){
      off[i] = run; cur[i] = run; run += v[u];
      if (i == len - 1) off[len] = run;
    }
  }
}

// ---------------- weight concat ----------------
__global__ void k_prep(const float* __restrict__ Wl, const float* __restrict__ bl,
                       const float* __restrict__ Wr, float* __restrict__ wcat,
                       float* __restrict__ bcat){
  int g = blockIdx.x * 256 + threadIdx.x;
  const int NW = 4 * 384 * 128;
  if (g < NW){
    int which = g / 49152;          // blk*2 + side
    int blk = which >> 1, side = which & 1;
    int idx = g % 49152;
    int k = idx >> 7;               // 0..383
    int c = idx & 127;
    int part = k >> 7, kk = k & 127;
    int tA = side == 0 ? 0 : 1;
    int tB = side == 0 ? 2 : 3;
    float v;
    if (part == 0)      v = 0.5f * Wl[(((blk*4 + tA)*128 + c)*128) + kk];
    else if (part == 1) v = 0.5f * Wl[(((blk*4 + tB)*128 + c)*128) + kk];
    else v = 0.5f * (Wr[(((blk*4 + tA)*128 + c)*128) + kk] + Wr[(((blk*4 + tB)*128 + c)*128) + kk]);
    wcat[which*49152 + k*128 + c] = v;
  } else if (g < NW + 512){
    int i = g - NW;
    int which = i >> 7;
    int blk = which >> 1, side = which & 1;
    int c = i & 127;
    int tA = side == 0 ? 0 : 1;
    int tB = side == 0 ? 2 : 3;
    bcat[which*128 + c] = 0.5f * (bl[(blk*4 + tA)*128 + c] + bl[(blk*4 + tB)*128 + c]);
  }
}

// ---------------- fused gather-mean + GEMM ----------------
// 32 rows x 128 cols per block. 256 threads = 8 row-groups x 32 col-groups;
// each thread: 4 rows x 4 cols. LDS = As 16.9KB + Bs 8KB = 25KB -> 5 blocks/CU.
__global__ __launch_bounds__(256, 5) void k_gemm(
    int M,
    const int* __restrict__ off0, const int* __restrict__ csr0, const float* __restrict__ tab0,
    const float* __restrict__ sc0, const float* __restrict__ sh0,
    const int* __restrict__ off1, const int* __restrict__ csr1, const float* __restrict__ tab1,
    const float* __restrict__ sc1, const float* __restrict__ sh1,
    const float* __restrict__ tabd, const float* __restrict__ scd, const float* __restrict__ shd,
    const float* __restrict__ W, const float* __restrict__ bias,
    float* __restrict__ out)
{
  __shared__ float As[32][132];   // +4 pad: tr-stride 528B -> distinct banks, 16B aligned rows
  __shared__ float Bs[16][128];
  const int tid = threadIdx.x;
  const int tr = tid >> 5;        // 0..7  (rows tr*4 .. tr*4+3)
  const int tc = tid & 31;        // 0..31 (cols tc*4 .. tc*4+3)
  const int row0 = blockIdx.x * 32;
  const int lane = tid & 63;
  const int wave = tid >> 6;
  const int sub = lane >> 5;      // half-wave: 32 lanes x float4 = one 128-f32 row
  const int li = lane & 31;
  float acc[4][4] = {};

  for (int part = 0; part < 3; ++part){
    __syncthreads();              // previous part's As/Bs reads complete
    const int* off; const int* csr; const float* tab; const float* sc; const float* sh;
    if (part == 0){ off = off0; csr = csr0; tab = tab0; sc = sc0; sh = sh0; }
    else if (part == 1){ off = off1; csr = csr1; tab = tab1; sc = sc1; sh = sh1; }
    else { off = nullptr; csr = nullptr; tab = tabd; sc = scd; sh = shd; }
    const bool bn = (sc != nullptr);
    float4 scv = make_float4(1.f,1.f,1.f,1.f), shv = make_float4(0.f,0.f,0.f,0.f);
    if (bn){ scv = *(const float4*)(sc + 4*li); shv = *(const float4*)(sh + 4*li); }

    // each wave stages 8 rows, two at a time (half-wave per row)
    for (int rr = 0; rr < 4; ++rr){
      int r = (wave << 3) + (rr << 1) + sub;
      int row = row0 + r;
      float4 v0 = make_float4(0.f,0.f,0.f,0.f);
      if (row < M){
        if (part < 2){
          int s = off[row], e = off[row+1];
          int n = e - s;
          float4 v1 = make_float4(0.f,0.f,0.f,0.f);
          int i = s;
          if (bn){
            for (; i + 4 <= e; i += 4){       // 4 loads in flight
              int s0 = csr[i], s1 = csr[i+1], s2 = csr[i+2], s3 = csr[i+3];
              float4 x0 = *(const float4*)(tab + (size_t)s0*FH + 4*li);
              float4 x1 = *(const float4*)(tab + (size_t)s1*FH + 4*li);
              float4 x2 = *(const float4*)(tab + (size_t)s2*FH + 4*li);
              float4 x3 = *(const float4*)(tab + (size_t)s3*FH + 4*li);
              v0.x += lrelu(fmaf(x0.x, scv.x, shv.x));
              v0.y += lrelu(fmaf(x0.y, scv.y, shv.y));
              v0.z += lrelu(fmaf(x0.z, scv.z, shv.z));
              v0.w += lrelu(fmaf(x0.w, scv.w, shv.w));
              v1.x += lrelu(fmaf(x1.x, scv.x, shv.x));
              v1.y += lrelu(fmaf(x1.y, scv.y, shv.y));
              v1.z += lrelu(fmaf(x1.z, scv.z, shv.z));
              v1.w += lrelu(fmaf(x1.w, scv.w, shv.w));
              v0.x += lrelu(fmaf(x2.x, scv.x, shv.x));
              v0.y += lrelu(fmaf(x2.y, scv.y, shv.y));
              v0.z += lrelu(fmaf(x2.z, scv.z, shv.z));
              v0.w += lrelu(fmaf(x2.w, scv.w, shv.w));
              v1.x += lrelu(fmaf(x3.x, scv.x, shv.x));
              v1.y += lrelu(fmaf(x3.y, scv.y, shv.y));
              v1.z += lrelu(fmaf(x3.z, scv.z, shv.z));
              v1.w += lrelu(fmaf(x3.w, scv.w, shv.w));
            }
            for (; i < e; ++i){
              int s0 = csr[i];
              float4 x0 = *(const float4*)(tab + (size_t)s0*FH + 4*li);
              v0.x += lrelu(fmaf(x0.x, scv.x, shv.x));
              v0.y += lrelu(fmaf(x0.y, scv.y, shv.y));
              v0.z += lrelu(fmaf(x0.z, scv.z, shv.z));
              v0.w += lrelu(fmaf(x0.w, scv.w, shv.w));
            }
          } else {
            for (; i + 4 <= e; i += 4){
              int s0 = csr[i], s1 = csr[i+1], s2 = csr[i+2], s3 = csr[i+3];
              float4 x0 = *(const float4*)(tab + (size_t)s0*FH + 4*li);
              float4 x1 = *(const float4*)(tab + (size_t)s1*FH + 4*li);
              float4 x2 = *(const float4*)(tab + (size_t)s2*FH + 4*li);
              float4 x3 = *(const float4*)(tab + (size_t)s3*FH + 4*li);
              v0.x += x0.x; v0.y += x0.y; v0.z += x0.z; v0.w += x0.w;
              v1.x += x1.x; v1.y += x1.y; v1.z += x1.z; v1.w += x1.w;
              v0.x += x2.x; v0.y += x2.y; v0.z += x2.z; v0.w += x2.w;
              v1.x += x3.x; v1.y += x3.y; v1.z += x3.z; v1.w += x3.w;
            }
            for (; i < e; ++i){
              int s0 = csr[i];
              float4 x0 = *(const float4*)(tab + (size_t)s0*FH + 4*li);
              v0.x += x0.x; v0.y += x0.y; v0.z += x0.z; v0.w += x0.w;
            }
          }
          float inv = 1.f / (float)(n > 1 ? n : 1);
          v0.x = (v0.x + v1.x) * inv;
          v0.y = (v0.y + v1.y) * inv;
          v0.z = (v0.z + v1.z) * inv;
          v0.w = (v0.w + v1.w) * inv;
        } else {
          float4 x = *(const float4*)(tabd + (size_t)row*FH + 4*li);
          if (bn){
            v0.x = lrelu(fmaf(x.x, scv.x, shv.x));
            v0.y = lrelu(fmaf(x.y, scv.y, shv.y));
            v0.z = lrelu(fmaf(x.z, scv.z, shv.z));
            v0.w = lrelu(fmaf(x.w, scv.w, shv.w));
          } else v0 = x;
        }
      }
      *(float4*)&As[r][4*li] = v0;
    }
    __syncthreads();

    for (int kc = 0; kc < 8; ++kc){   // 8 chunks of 16 k-rows
      if (kc) __syncthreads();        // prior chunk's Bs reads complete
      const float* wsrc = W + (part*128 + kc*16)*128;
      {
        int idx = tid * 8;
        *(float4*)((float*)Bs + idx)     = *(const float4*)(wsrc + idx);
        *(float4*)((float*)Bs + idx + 4) = *(const float4*)(wsrc + idx + 4);
      }
      __syncthreads();
      #pragma unroll
      for (int k = 0; k < 16; ++k){
        float av[4];
        #pragma unroll
        for (int j = 0; j < 4; ++j) av[j] = As[tr*4 + j][kc*16 + k];
        float4 b = *(const float4*)&Bs[k][tc*4];
        #pragma unroll
        for (int j = 0; j < 4; ++j){
          acc[j][0] = fmaf(av[j], b.x, acc[j][0]);
          acc[j][1] = fmaf(av[j], b.y, acc[j][1]);
          acc[j][2] = fmaf(av[j], b.z, acc[j][2]);
          acc[j][3] = fmaf(av[j], b.w, acc[j][3]);
        }
      }
    }
  }

  float4 bi = *(const float4*)&bias[tc*4];
  #pragma unroll
  for (int j = 0; j < 4; ++j){
    int row = row0 + tr*4 + j;
    if (row < M){
      float4 o = make_float4(acc[j][0]+bi.x, acc[j][1]+bi.y, acc[j][2]+bi.z, acc[j][3]+bi.w);
      *(float4*)(out + (size_t)row*FH + tc*4) = o;
    }
  }
}

// ---------------- BN ----------------
__global__ void k_bn_stats(const float* __restrict__ x, int M,
                           float* __restrict__ gsum, float* __restrict__ gsq){
  int t = threadIdx.x;
  int f = t & 127;
  int half = t >> 7;
  float s = 0.f, q = 0.f;
  for (int row = blockIdx.x*2 + half; row < M; row += gridDim.x*2){
    float v = x[(size_t)row*FH + f];
    s += v; q += v*v;
  }
  __shared__ float red[256];
  red[t] = s; __syncthreads();
  if (t < 128) atomicAdd(&gsum[t], red[t] + red[t+128]);
  __syncthreads();
  red[t] = q; __syncthreads();
  if (t < 128) atomicAdd(&gsq[t], red[t] + red[t+128]);
}

__global__ void k_bn_finalize(const float* __restrict__ sF, const float* __restrict__ qF, float invMF,
                              const float* __restrict__ sH, const float* __restrict__ qH, float invMH,
                              const float* __restrict__ gamma, const float* __restrict__ beta,
                              float* scF, float* shF, float* scH, float* shH){
  int t = threadIdx.x;
  if (t < 128){
    float mu = sF[t] * invMF;
    float var = qF[t] * invMF - mu*mu;
    float s = gamma[t] * rsqrtf(var + BNEPS);
    scF[t] = s; shF[t] = beta[t] - mu*s;
  } else {
    int f = t - 128;
    float mu = sH[f] * invMH;
    float var = qH[f] * invMH - mu*mu;
    float s = gamma[f] * rsqrtf(var + BNEPS);
    scH[f] = s; shH[f] = beta[f] - mu*s;
  }
}

__global__ void k_apply(float* __restrict__ x, int n4,
                        const float* __restrict__ sc, const float* __restrict__ shf){
  int g = blockIdx.x * blockDim.x + threadIdx.x;
  int stride = gridDim.x * blockDim.x;
  for (int i = g; i < n4; i += stride){
    float4 v = ((const float4*)x)[i];
    int f = (i*4) & 127;
    float4 s = *(const float4*)(sc + f);
    float4 b = *(const float4*)(shf + f);
    v.x = lrelu(fmaf(v.x, s.x, b.x));
    v.y = lrelu(fmaf(v.y, s.y, b.y));
    v.z = lrelu(fmaf(v.z, s.z, b.z));
    v.w = lrelu(fmaf(v.w, s.w, b.w));
    ((float4*)x)[i] = v;
  }
}

// ---------------- launch ----------------
extern "C" void kernel_launch(void* const* d_in, const int* in_sizes, int n_in,
                              void* d_out, int out_size, void* d_ws, size_t ws_size,
                              hipStream_t stream) {
  const float* x_host = (const float*)d_in[0];
  const float* x_flow = (const float*)d_in[1];
  const int* ei_s  = (const int*)d_in[2];
  const int* ei_rv = (const int*)d_in[3];
  const int* ei_p  = (const int*)d_in[4];
  const int* ei_rc = (const int*)d_in[5];
  const float* Wl    = (const float*)d_in[6];
  const float* bl    = (const float*)d_in[7];
  const float* Wr    = (const float*)d_in[8];
  const float* gamma = (const float*)d_in[9];
  const float* beta  = (const float*)d_in[10];

  const int NH = in_sizes[0] / FH;   // 50000
  const int NF = in_sizes[1] / FH;   // 200000
  const int Es  = in_sizes[2] / 2;
  const int Erv = in_sizes[3] / 2;
  const int Ep  = in_sizes[4] / 2;
  const int Erc = in_sizes[5] / 2;

  float* out_h = (float*)d_out;
  float* out_f = (float*)d_out + (size_t)NH * FH;

  char* p = (char*)d_ws;
  auto alloc = [&](size_t bytes) -> void* {
    void* r = (void*)p;
    p += (bytes + 255) & ~(size_t)255;
    return r;
  };
  float* f_raw0 = (float*)alloc((size_t)NF * FH * 4);
  float* h_raw0 = (float*)alloc((size_t)NH * FH * 4);
  float* wcat   = (float*)alloc((size_t)4 * 49152 * 4);
  float* bcat   = (float*)alloc(512 * 4);
  float* stats  = (float*)alloc(1024 * 4);
  float* ssbuf  = (float*)alloc(1024 * 4);
  int* cnt_s = (int*)alloc((size_t)NF * 4);
  int* cnt_p = (int*)alloc((size_t)NF * 4);
  int* cnt_r = (int*)alloc((size_t)NH * 4);
  int* cnt_q = (int*)alloc((size_t)NH * 4);
  int* off_s = (int*)alloc((size_t)(NF+1) * 4);
  int* off_p = (int*)alloc((size_t)(NF+1) * 4);
  int* off_r = (int*)alloc((size_t)(NH+1) * 4);
  int* off_q = (int*)alloc((size_t)(NH+1) * 4);
  int* cur_s = (int*)alloc((size_t)NF * 4);
  int* cur_p = (int*)alloc((size_t)NF * 4);
  int* cur_r = (int*)alloc((size_t)NH * 4);
  int* cur_q = (int*)alloc((size_t)NH * 4);
  int* csr_s = (int*)alloc((size_t)Es * 4);
  int* csr_p = (int*)alloc((size_t)Ep * 4);
  int* csr_r = (int*)alloc((size_t)Erv * 4);
  int* csr_q = (int*)alloc((size_t)Erc * 4);
  int* ssum  = (int*)alloc(1024 * 4);

  size_t cnt_bytes = (char*)cnt_q + (size_t)NH*4 - (char*)cnt_s;
  hipMemsetAsync(cnt_s, 0, cnt_bytes, stream);
  hipMemsetAsync(stats, 0, 1024 * 4, stream);

  k_prep<<<(4*384*128 + 512 + 255)/256, 256, 0, stream>>>(Wl, bl, Wr, wcat, bcat);

  k_hist<<<(Es +255)/256, 256, 0, stream>>>(ei_s  + Es,  Es,  cnt_s);
  k_hist<<<(Ep +255)/256, 256, 0, stream>>>(ei_p  + Ep,  Ep,  cnt_p);
  k_hist<<<(Erv+255)/256, 256, 0, stream>>>(ei_rv + Erv, Erv, cnt_r);
  k_hist<<<(Erc+255)/256, 256, 0, stream>>>(ei_rc + Erc, Erc, cnt_q);

  int nchF = (NF + 1023) / 1024;   // 196
  int nchH = (NH + 1023) / 1024;   // 49
  dim3 gscan(nchF, 4);
  k_chunk_sums<<<gscan, 256, 0, stream>>>(cnt_s, cnt_p, cnt_r, cnt_q, NF, NF, NH, NH, ssum);
  k_scan_sums<<<4, 256, 0, stream>>>(ssum, nchF, nchF, nchH, nchH);
  k_write_offsets<<<gscan, 256, 0, stream>>>(cnt_s, cnt_p, cnt_r, cnt_q,
                                             off_s, off_p, off_r, off_q,
                                             cur_s, cur_p, cur_r, cur_q,
                                             NF, NF, NH, NH, ssum);

  k_fill<<<(Es +255)/256, 256, 0, stream>>>(ei_s,  ei_s  + Es,  Es,  cur_s, csr_s);
  k_fill<<<(Ep +255)/256, 256, 0, stream>>>(ei_p,  ei_p  + Ep,  Ep,  cur_p, csr_p);
  k_fill<<<(Erv+255)/256, 256, 0, stream>>>(ei_rv, ei_rv + Erv, Erv, cur_r, csr_r);
  k_fill<<<(Erc+255)/256, 256, 0, stream>>>(ei_rc, ei_rc + Erc, Erc, cur_q, csr_q);

  int gF = (NF + 31) / 32;   // 6250
  int gH = (NH + 31) / 32;   // 1563

  for (int blk = 0; blk < 2; ++blk){
    const float* fcur = blk ? f_raw0 : x_flow;
    const float* hcur = blk ? h_raw0 : x_host;
    const float* scF = blk ? ssbuf + 0   : nullptr;
    const float* shF = blk ? ssbuf + 128 : nullptr;
    const float* scH = blk ? ssbuf + 256 : nullptr;
    const float* shH = blk ? ssbuf + 384 : nullptr;
    float* outF = blk ? out_f : f_raw0;
    float* outH = blk ? out_h : h_raw0;
    const float* wf = wcat + (blk*2 + 0) * 49152;
    const float* wh = wcat + (blk*2 + 1) * 49152;
    const float* bf = bcat + (blk*2 + 0) * 128;
    const float* bh = bcat + (blk*2 + 1) * 128;

    k_gemm<<<gF, 256, 0, stream>>>(NF,
        off_s, csr_s, hcur, scH, shH,
        off_p, csr_p, fcur, scF, shF,
        fcur, scF, shF,
        wf, bf, outF);
    k_gemm<<<gH, 256, 0, stream>>>(NH,
        off_r, csr_r, fcur, scF, shF,
        off_q, csr_q, fcur, scF, shF,
        hcur, scH, shH,
        wh, bh, outH);

    float* st = stats + blk * 512;
    k_bn_stats<<<512, 256, 0, stream>>>(outF, NF, st + 0,   st + 128);
    k_bn_stats<<<512, 256, 0, stream>>>(outH, NH, st + 256, st + 384);
    float* ss = ssbuf + blk * 512;
    k_bn_finalize<<<1, 256, 0, stream>>>(st + 0, st + 128, 1.f/(float)NF,
                                         st + 256, st + 384, 1.f/(float)NH,
                                         gamma + blk*128, beta + blk*128,
                                         ss + 0, ss + 128, ss + 256, ss + 384);
  }

  k_apply<<<2048, 256, 0, stream>>>(out_f, NF * FH / 4, ssbuf + 512 + 0,   ssbuf + 512 + 128);
  k_apply<<<2048, 256, 0, stream>>>(out_h, NH * FH / 4, ssbuf + 512 + 256, ssbuf + 512 + 384);
}

// Round 3
// 2296.716 us; speedup vs baseline: 1.4662x; 1.0270x over previous
//
#include <hip/hip_runtime.h>

#define FH 128
#define NEG 0.01f
#define BNEPS 1e-5f

typedef unsigned int uint32;
typedef unsigned short ushort16;

__device__ __forceinline__ float lrelu(float v){ return v >= 0.f ? v : NEG * v; }
// bf16 (stored as ushort) helpers
__device__ __forceinline__ float bfl(uint32 u){ return __uint_as_float(u << 16); }          // low half
__device__ __forceinline__ float bfh(uint32 u){ return __uint_as_float(u & 0xffff0000u); }  // high half
__device__ __forceinline__ ushort16 f2bf(float f){
  uint32 u = __float_as_uint(f);
  u += 0x7fffu + ((u >> 16) & 1u);   // RNE
  return (ushort16)(u >> 16);
}

// ---------------- fp32 -> bf16 table conversion ----------------
__global__ void k_cvt(const float* __restrict__ x, ushort16* __restrict__ t, int n4){
  int g = blockIdx.x * 256 + threadIdx.x;
  int stride = gridDim.x * 256;
  for (int i = g; i < n4; i += stride){
    float4 v = ((const float4*)x)[i];
    ushort4 p;
    p.x = f2bf(v.x); p.y = f2bf(v.y); p.z = f2bf(v.z); p.w = f2bf(v.w);
    ((ushort4*)t)[i] = p;
  }
}

// ---------------- CSR build ----------------
__global__ void k_hist(const int* __restrict__ dst, int E, int* __restrict__ cnt){
  int i = blockIdx.x * 256 + threadIdx.x;
  if (i < E) atomicAdd(&cnt[dst[i]], 1);
}

__global__ void k_fill(const int* __restrict__ src, const int* __restrict__ dst, int E,
                       int* __restrict__ cur, int* __restrict__ csr){
  int i = blockIdx.x * 256 + threadIdx.x;
  if (i < E){
    int slot = atomicAdd(&cur[dst[i]], 1);
    csr[slot] = src[i];
  }
}

// chunk = 1024 elems, 256 threads x 4
__global__ void k_chunk_sums(const int* c0, const int* c1, const int* c2, const int* c3,
                             int l0, int l1, int l2, int l3, int* __restrict__ sums){
  int a = blockIdx.y;
  const int* c = a==0?c0 : a==1?c1 : a==2?c2 : c3;
  int len     = a==0?l0 : a==1?l1 : a==2?l2 : l3;
  int base = blockIdx.x * 1024;
  if (base >= len) return;
  int t = threadIdx.x;
  int s = 0;
  #pragma unroll
  for (int u = 0; u < 4; ++u){ int i = base + t*4 + u; if (i < len) s += c[i]; }
  __shared__ int red[256];
  red[t] = s; __syncthreads();
  for (int o = 128; o > 0; o >>= 1){ if (t < o) red[t] += red[t+o]; __syncthreads(); }
  if (t == 0) sums[a*256 + blockIdx.x] = red[0];
}

__global__ void k_scan_sums(int* sums, int n0, int n1, int n2, int n3){
  int a = blockIdx.x;
  int n = a==0?n0 : a==1?n1 : a==2?n2 : n3;
  int t = threadIdx.x;
  __shared__ int shm[256];
  shm[t] = (t < n) ? sums[a*256 + t] : 0;
  __syncthreads();
  for (int o = 1; o < 256; o <<= 1){
    int x = shm[t];
    if (t >= o) x += shm[t-o];
    __syncthreads();
    shm[t] = x;
    __syncthreads();
  }
  sums[a*256 + t] = t ? shm[t-1] : 0;
}

__global__ void k_write_offsets(const int* c0, const int* c1, const int* c2, const int* c3,
                                int* o0, int* o1, int* o2, int* o3,
                                int* u0, int* u1, int* u2, int* u3,
                                int l0, int l1, int l2, int l3,
                                const int* __restrict__ sums){
  int a = blockIdx.y;
  const int* c = a==0?c0 : a==1?c1 : a==2?c2 : c3;
  int* off     = a==0?o0 : a==1?o1 : a==2?o2 : o3;
  int* cur     = a==0?u0 : a==1?u1 : a==2?u2 : u3;
  int len      = a==0?l0 : a==1?l1 : a==2?l2 : l3;
  int base = blockIdx.x * 1024;
  if (base >= len) return;
  int t = threadIdx.x;
  int v[4]; int s = 0;
  #pragma unroll
  for (int u = 0; u < 4; ++u){ int i = base + t*4 + u; v[u] = (i < len) ? c[i] : 0; s += v[u]; }
  __shared__ int shm[256];
  shm[t] = s; __syncthreads();
  for (int o = 1; o < 256; o <<= 1){
    int x = shm[t];
    if (t >= o) x += shm[t-o];
    __syncthreads();
    shm[t] = x;
    __syncthreads();
  }
  int run = (t ? shm[t-1] : 0) + sums[a*256 + blockIdx.x];
  #pragma unroll
  for (int u = 0; u < 4; ++u){
    int i = base + t*4 + u;
    if (i < len){
      off[i] = run; cur[i] = run; run += v[u];
      if (i == len - 1) off[len] = run;
    }
  }
}

// ---------------- weight concat ----------------
__global__ void k_prep(const float* __restrict__ Wl, const float* __restrict__ bl,
                       const float* __restrict__ Wr, float* __restrict__ wcat,
                       float* __restrict__ bcat){
  int g = blockIdx.x * 256 + threadIdx.x;
  const int NW = 4 * 384 * 128;
  if (g < NW){
    int which = g / 49152;          // blk*2 + side
    int blk = which >> 1, side = which & 1;
    int idx = g % 49152;
    int k = idx >> 7;               // 0..383
    int c = idx & 127;
    int part = k >> 7, kk = k & 127;
    int tA = side == 0 ? 0 : 1;
    int tB = side == 0 ? 2 : 3;
    float v;
    if (part == 0)      v = 0.5f * Wl[(((blk*4 + tA)*128 + c)*128) + kk];
    else if (part == 1) v = 0.5f * Wl[(((blk*4 + tB)*128 + c)*128) + kk];
    else v = 0.5f * (Wr[(((blk*4 + tA)*128 + c)*128) + kk] + Wr[(((blk*4 + tB)*128 + c)*128) + kk]);
    wcat[which*49152 + k*128 + c] = v;
  } else if (g < NW + 512){
    int i = g - NW;
    int which = i >> 7;
    int blk = which >> 1, side = which & 1;
    int c = i & 127;
    int tA = side == 0 ? 0 : 1;
    int tB = side == 0 ? 2 : 3;
    bcat[which*128 + c] = 0.5f * (bl[(blk*4 + tA)*128 + c] + bl[(blk*4 + tB)*128 + c]);
  }
}

// ---------------- fused gather-mean + GEMM ----------------
// 32 rows x 128 cols per block; gather tables are bf16 (ushort). One full wave
// stages one row at a time (uniform loop bounds -> no divergence), lane = 2 feats.
__global__ __launch_bounds__(256, 5) void k_gemm(
    int M,
    const int* __restrict__ off0, const int* __restrict__ csr0, const ushort16* __restrict__ tab0,
    const float* __restrict__ sc0, const float* __restrict__ sh0,
    const int* __restrict__ off1, const int* __restrict__ csr1, const ushort16* __restrict__ tab1,
    const float* __restrict__ sc1, const float* __restrict__ sh1,
    const ushort16* __restrict__ tabd, const float* __restrict__ scd, const float* __restrict__ shd,
    const float* __restrict__ W, const float* __restrict__ bias,
    float* __restrict__ out32, ushort16* __restrict__ out16)
{
  __shared__ float As[32][132];   // +4 pad
  __shared__ float Bs[16][128];
  const int tid = threadIdx.x;
  const int tr = tid >> 5;        // 0..7  (rows tr*4 .. tr*4+3)
  const int tc = tid & 31;        // 0..31 (cols tc*4 .. tc*4+3)
  const int row0 = blockIdx.x * 32;
  const int lane = tid & 63;
  const int wave = tid >> 6;
  float acc[4][4] = {};

  for (int part = 0; part < 3; ++part){
    __syncthreads();              // previous part's As/Bs reads complete
    const int* off; const int* csr; const ushort16* tab; const float* sc; const float* sh;
    if (part == 0){ off = off0; csr = csr0; tab = tab0; sc = sc0; sh = sh0; }
    else if (part == 1){ off = off1; csr = csr1; tab = tab1; sc = sc1; sh = sh1; }
    else { off = nullptr; csr = nullptr; tab = tabd; sc = scd; sh = shd; }
    const bool bn = (sc != nullptr);
    float scx = 1.f, scy = 1.f, shx = 0.f, shy = 0.f;
    if (bn){
      scx = sc[2*lane]; scy = sc[2*lane+1];
      shx = sh[2*lane]; shy = sh[2*lane+1];
    }

    // each wave stages 8 rows, whole wave per row
    for (int rr = 0; rr < 8; ++rr){
      int r = (wave << 3) + rr;
      int row = row0 + r;
      float vx = 0.f, vy = 0.f;
      if (row < M){
        if (part < 2){
          int s = off[row], e = off[row+1];
          int n = e - s;
          float ux = 0.f, uy = 0.f;   // second accumulator pair
          int i = s;
          if (bn){
            for (; i + 4 <= e; i += 4){       // 4 x 256B loads in flight
              int s0 = csr[i], s1 = csr[i+1], s2 = csr[i+2], s3 = csr[i+3];
              uint32 x0 = *(const uint32*)(tab + (size_t)s0*FH + 2*lane);
              uint32 x1 = *(const uint32*)(tab + (size_t)s1*FH + 2*lane);
              uint32 x2 = *(const uint32*)(tab + (size_t)s2*FH + 2*lane);
              uint32 x3 = *(const uint32*)(tab + (size_t)s3*FH + 2*lane);
              vx += lrelu(fmaf(bfl(x0), scx, shx)); vy += lrelu(fmaf(bfh(x0), scy, shy));
              ux += lrelu(fmaf(bfl(x1), scx, shx)); uy += lrelu(fmaf(bfh(x1), scy, shy));
              vx += lrelu(fmaf(bfl(x2), scx, shx)); vy += lrelu(fmaf(bfh(x2), scy, shy));
              ux += lrelu(fmaf(bfl(x3), scx, shx)); uy += lrelu(fmaf(bfh(x3), scy, shy));
            }
            for (; i < e; ++i){
              int s0 = csr[i];
              uint32 x0 = *(const uint32*)(tab + (size_t)s0*FH + 2*lane);
              vx += lrelu(fmaf(bfl(x0), scx, shx)); vy += lrelu(fmaf(bfh(x0), scy, shy));
            }
          } else {
            for (; i + 4 <= e; i += 4){
              int s0 = csr[i], s1 = csr[i+1], s2 = csr[i+2], s3 = csr[i+3];
              uint32 x0 = *(const uint32*)(tab + (size_t)s0*FH + 2*lane);
              uint32 x1 = *(const uint32*)(tab + (size_t)s1*FH + 2*lane);
              uint32 x2 = *(const uint32*)(tab + (size_t)s2*FH + 2*lane);
              uint32 x3 = *(const uint32*)(tab + (size_t)s3*FH + 2*lane);
              vx += bfl(x0); vy += bfh(x0);
              ux += bfl(x1); uy += bfh(x1);
              vx += bfl(x2); vy += bfh(x2);
              ux += bfl(x3); uy += bfh(x3);
            }
            for (; i < e; ++i){
              int s0 = csr[i];
              uint32 x0 = *(const uint32*)(tab + (size_t)s0*FH + 2*lane);
              vx += bfl(x0); vy += bfh(x0);
            }
          }
          float inv = 1.f / (float)(n > 1 ? n : 1);
          vx = (vx + ux) * inv;
          vy = (vy + uy) * inv;
        } else {
          uint32 x = *(const uint32*)(tabd + (size_t)row*FH + 2*lane);
          float fx = bfl(x), fy = bfh(x);
          if (bn){
            vx = lrelu(fmaf(fx, scx, shx));
            vy = lrelu(fmaf(fy, scy, shy));
          } else { vx = fx; vy = fy; }
        }
      }
      *(float2*)&As[r][2*lane] = make_float2(vx, vy);
    }
    __syncthreads();

    for (int kc = 0; kc < 8; ++kc){   // 8 chunks of 16 k-rows
      if (kc) __syncthreads();        // prior chunk's Bs reads complete
      const float* wsrc = W + (part*128 + kc*16)*128;
      {
        int idx = tid * 8;
        *(float4*)((float*)Bs + idx)     = *(const float4*)(wsrc + idx);
        *(float4*)((float*)Bs + idx + 4) = *(const float4*)(wsrc + idx + 4);
      }
      __syncthreads();
      #pragma unroll
      for (int k = 0; k < 16; ++k){
        float av[4];
        #pragma unroll
        for (int j = 0; j < 4; ++j) av[j] = As[tr*4 + j][kc*16 + k];
        float4 b = *(const float4*)&Bs[k][tc*4];
        #pragma unroll
        for (int j = 0; j < 4; ++j){
          acc[j][0] = fmaf(av[j], b.x, acc[j][0]);
          acc[j][1] = fmaf(av[j], b.y, acc[j][1]);
          acc[j][2] = fmaf(av[j], b.z, acc[j][2]);
          acc[j][3] = fmaf(av[j], b.w, acc[j][3]);
        }
      }
    }
  }

  float4 bi = *(const float4*)&bias[tc*4];
  #pragma unroll
  for (int j = 0; j < 4; ++j){
    int row = row0 + tr*4 + j;
    if (row < M){
      float4 o = make_float4(acc[j][0]+bi.x, acc[j][1]+bi.y, acc[j][2]+bi.z, acc[j][3]+bi.w);
      if (out32) *(float4*)(out32 + (size_t)row*FH + tc*4) = o;
      if (out16){
        ushort4 p;
        p.x = f2bf(o.x); p.y = f2bf(o.y); p.z = f2bf(o.z); p.w = f2bf(o.w);
        *(ushort4*)(out16 + (size_t)row*FH + tc*4) = p;
      }
    }
  }
}

// ---------------- BN ----------------
__global__ void k_bn_stats(const float* __restrict__ x, int M,
                           float* __restrict__ gsum, float* __restrict__ gsq){
  int t = threadIdx.x;
  int f = t & 127;
  int half = t >> 7;
  float s = 0.f, q = 0.f;
  for (int row = blockIdx.x*2 + half; row < M; row += gridDim.x*2){
    float v = x[(size_t)row*FH + f];
    s += v; q += v*v;
  }
  __shared__ float red[256];
  red[t] = s; __syncthreads();
  if (t < 128) atomicAdd(&gsum[t], red[t] + red[t+128]);
  __syncthreads();
  red[t] = q; __syncthreads();
  if (t < 128) atomicAdd(&gsq[t], red[t] + red[t+128]);
}

__global__ void k_bn_stats16(const ushort16* __restrict__ x, int M,
                             float* __restrict__ gsum, float* __restrict__ gsq){
  int t = threadIdx.x;
  int f = t & 127;
  int half = t >> 7;
  float s = 0.f, q = 0.f;
  for (int row = blockIdx.x*2 + half; row < M; row += gridDim.x*2){
    float v = __uint_as_float(((uint32)x[(size_t)row*FH + f]) << 16);
    s += v; q += v*v;
  }
  __shared__ float red[256];
  red[t] = s; __syncthreads();
  if (t < 128) atomicAdd(&gsum[t], red[t] + red[t+128]);
  __syncthreads();
  red[t] = q; __syncthreads();
  if (t < 128) atomicAdd(&gsq[t], red[t] + red[t+128]);
}

__global__ void k_bn_finalize(const float* __restrict__ sF, const float* __restrict__ qF, float invMF,
                              const float* __restrict__ sH, const float* __restrict__ qH, float invMH,
                              const float* __restrict__ gamma, const float* __restrict__ beta,
                              float* scF, float* shF, float* scH, float* shH){
  int t = threadIdx.x;
  if (t < 128){
    float mu = sF[t] * invMF;
    float var = qF[t] * invMF - mu*mu;
    float s = gamma[t] * rsqrtf(var + BNEPS);
    scF[t] = s; shF[t] = beta[t] - mu*s;
  } else {
    int f = t - 128;
    float mu = sH[f] * invMH;
    float var = qH[f] * invMH - mu*mu;
    float s = gamma[f] * rsqrtf(var + BNEPS);
    scH[f] = s; shH[f] = beta[f] - mu*s;
  }
}

__global__ void k_apply(float* __restrict__ x, int n4,
                        const float* __restrict__ sc, const float* __restrict__ shf){
  int g = blockIdx.x * blockDim.x + threadIdx.x;
  int stride = gridDim.x * blockDim.x;
  for (int i = g; i < n4; i += stride){
    float4 v = ((const float4*)x)[i];
    int f = (i*4) & 127;
    float4 s = *(const float4*)(sc + f);
    float4 b = *(const float4*)(shf + f);
    v.x = lrelu(fmaf(v.x, s.x, b.x));
    v.y = lrelu(fmaf(v.y, s.y, b.y));
    v.z = lrelu(fmaf(v.z, s.z, b.z));
    v.w = lrelu(fmaf(v.w, s.w, b.w));
    ((float4*)x)[i] = v;
  }
}

// ---------------- launch ----------------
extern "C" void kernel_launch(void* const* d_in, const int* in_sizes, int n_in,
                              void* d_out, int out_size, void* d_ws, size_t ws_size,
                              hipStream_t stream) {
  const float* x_host = (const float*)d_in[0];
  const float* x_flow = (const float*)d_in[1];
  const int* ei_s  = (const int*)d_in[2];
  const int* ei_rv = (const int*)d_in[3];
  const int* ei_p  = (const int*)d_in[4];
  const int* ei_rc = (const int*)d_in[5];
  const float* Wl    = (const float*)d_in[6];
  const float* bl    = (const float*)d_in[7];
  const float* Wr    = (const float*)d_in[8];
  const float* gamma = (const float*)d_in[9];
  const float* beta  = (const float*)d_in[10];

  const int NH = in_sizes[0] / FH;   // 50000
  const int NF = in_sizes[1] / FH;   // 200000
  const int Es  = in_sizes[2] / 2;
  const int Erv = in_sizes[3] / 2;
  const int Ep  = in_sizes[4] / 2;
  const int Erc = in_sizes[5] / 2;

  float* out_h = (float*)d_out;
  float* out_f = (float*)d_out + (size_t)NH * FH;

  char* p = (char*)d_ws;
  auto alloc = [&](size_t bytes) -> void* {
    void* r = (void*)p;
    p += (bytes + 255) & ~(size_t)255;
    return r;
  };
  ushort16* xf16  = (ushort16*)alloc((size_t)NF * FH * 2);  // bf16 input tables
  ushort16* xh16  = (ushort16*)alloc((size_t)NH * FH * 2);
  ushort16* f16_0 = (ushort16*)alloc((size_t)NF * FH * 2);  // block-0 raw outputs (bf16)
  ushort16* h16_0 = (ushort16*)alloc((size_t)NH * FH * 2);
  float* wcat   = (float*)alloc((size_t)4 * 49152 * 4);
  float* bcat   = (float*)alloc(512 * 4);
  float* stats  = (float*)alloc(1024 * 4);
  float* ssbuf  = (float*)alloc(1024 * 4);
  int* cnt_s = (int*)alloc((size_t)NF * 4);
  int* cnt_p = (int*)alloc((size_t)NF * 4);
  int* cnt_r = (int*)alloc((size_t)NH * 4);
  int* cnt_q = (int*)alloc((size_t)NH * 4);
  int* off_s = (int*)alloc((size_t)(NF+1) * 4);
  int* off_p = (int*)alloc((size_t)(NF+1) * 4);
  int* off_r = (int*)alloc((size_t)(NH+1) * 4);
  int* off_q = (int*)alloc((size_t)(NH+1) * 4);
  int* cur_s = (int*)alloc((size_t)NF * 4);
  int* cur_p = (int*)alloc((size_t)NF * 4);
  int* cur_r = (int*)alloc((size_t)NH * 4);
  int* cur_q = (int*)alloc((size_t)NH * 4);
  int* csr_s = (int*)alloc((size_t)Es * 4);
  int* csr_p = (int*)alloc((size_t)Ep * 4);
  int* csr_r = (int*)alloc((size_t)Erv * 4);
  int* csr_q = (int*)alloc((size_t)Erc * 4);
  int* ssum  = (int*)alloc(1024 * 4);

  size_t cnt_bytes = (char*)cnt_q + (size_t)NH*4 - (char*)cnt_s;
  hipMemsetAsync(cnt_s, 0, cnt_bytes, stream);
  hipMemsetAsync(stats, 0, 1024 * 4, stream);

  k_prep<<<(4*384*128 + 512 + 255)/256, 256, 0, stream>>>(Wl, bl, Wr, wcat, bcat);
  k_cvt<<<1024, 256, 0, stream>>>(x_flow, xf16, NF * FH / 4);
  k_cvt<<<1024, 256, 0, stream>>>(x_host, xh16, NH * FH / 4);

  k_hist<<<(Es +255)/256, 256, 0, stream>>>(ei_s  + Es,  Es,  cnt_s);
  k_hist<<<(Ep +255)/256, 256, 0, stream>>>(ei_p  + Ep,  Ep,  cnt_p);
  k_hist<<<(Erv+255)/256, 256, 0, stream>>>(ei_rv + Erv, Erv, cnt_r);
  k_hist<<<(Erc+255)/256, 256, 0, stream>>>(ei_rc + Erc, Erc, cnt_q);

  int nchF = (NF + 1023) / 1024;   // 196
  int nchH = (NH + 1023) / 1024;   // 49
  dim3 gscan(nchF, 4);
  k_chunk_sums<<<gscan, 256, 0, stream>>>(cnt_s, cnt_p, cnt_r, cnt_q, NF, NF, NH, NH, ssum);
  k_scan_sums<<<4, 256, 0, stream>>>(ssum, nchF, nchF, nchH, nchH);
  k_write_offsets<<<gscan, 256, 0, stream>>>(cnt_s, cnt_p, cnt_r, cnt_q,
                                             off_s, off_p, off_r, off_q,
                                             cur_s, cur_p, cur_r, cur_q,
                                             NF, NF, NH, NH, ssum);

  k_fill<<<(Es +255)/256, 256, 0, stream>>>(ei_s,  ei_s  + Es,  Es,  cur_s, csr_s);
  k_fill<<<(Ep +255)/256, 256, 0, stream>>>(ei_p,  ei_p  + Ep,  Ep,  cur_p, csr_p);
  k_fill<<<(Erv+255)/256, 256, 0, stream>>>(ei_rv, ei_rv + Erv, Erv, cur_r, csr_r);
  k_fill<<<(Erc+255)/256, 256, 0, stream>>>(ei_rc, ei_rc + Erc, Erc, cur_q, csr_q);

  int gF = (NF + 31) / 32;   // 6250
  int gH = (NH + 31) / 32;   // 1563

  for (int blk = 0; blk < 2; ++blk){
    const ushort16* fcur = blk ? f16_0 : xf16;
    const ushort16* hcur = blk ? h16_0 : xh16;
    const float* scF = blk ? ssbuf + 0   : nullptr;
    const float* shF = blk ? ssbuf + 128 : nullptr;
    const float* scH = blk ? ssbuf + 256 : nullptr;
    const float* shH = blk ? ssbuf + 384 : nullptr;
    float*    oF32 = blk ? out_f : nullptr;
    float*    oH32 = blk ? out_h : nullptr;
    ushort16* oF16 = blk ? nullptr : f16_0;
    ushort16* oH16 = blk ? nullptr : h16_0;
    const float* wf = wcat + (blk*2 + 0) * 49152;
    const float* wh = wcat + (blk*2 + 1) * 49152;
    const float* bf = bcat + (blk*2 + 0) * 128;
    const float* bh = bcat + (blk*2 + 1) * 128;

    k_gemm<<<gF, 256, 0, stream>>>(NF,
        off_s, csr_s, hcur, scH, shH,
        off_p, csr_p, fcur, scF, shF,
        fcur, scF, shF,
        wf, bf, oF32, oF16);
    k_gemm<<<gH, 256, 0, stream>>>(NH,
        off_r, csr_r, fcur, scF, shF,
        off_q, csr_q, fcur, scF, shF,
        hcur, scH, shH,
        wh, bh, oH32, oH16);

    float* st = stats + blk * 512;
    if (blk == 0){
      k_bn_stats16<<<512, 256, 0, stream>>>(f16_0, NF, st + 0,   st + 128);
      k_bn_stats16<<<512, 256, 0, stream>>>(h16_0, NH, st + 256, st + 384);
    } else {
      k_bn_stats<<<512, 256, 0, stream>>>(out_f, NF, st + 0,   st + 128);
      k_bn_stats<<<512, 256, 0, stream>>>(out_h, NH, st + 256, st + 384);
    }
    float* ss = ssbuf + blk * 512;
    k_bn_finalize<<<1, 256, 0, stream>>>(st + 0, st + 128, 1.f/(float)NF,
                                         st + 256, st + 384, 1.f/(float)NH,
                                         gamma + blk*128, beta + blk*128,
                                         ss + 0, ss + 128, ss + 256, ss + 384);
  }

  k_apply<<<2048, 256, 0, stream>>>(out_f, NF * FH / 4, ssbuf + 512 + 0,   ssbuf + 512 + 128);
  k_apply<<<2048, 256, 0, stream>>>(out_h, NH * FH / 4, ssbuf + 512 + 256, ssbuf + 512 + 384);
}

// Round 4
// 1985.980 us; speedup vs baseline: 1.6956x; 1.1565x over previous
//
#include <hip/hip_runtime.h>

#define FH 128
#define NEG 0.01f
#define BNEPS 1e-5f

typedef unsigned int uint32;
typedef unsigned short u16;
typedef __attribute__((ext_vector_type(8))) short bf16x8;
typedef __attribute__((ext_vector_type(4))) float f32x4;

__device__ __forceinline__ float lrelu(float v){ return v >= 0.f ? v : NEG * v; }
__device__ __forceinline__ float bfl(uint32 u){ return __uint_as_float(u << 16); }
__device__ __forceinline__ float bfh(uint32 u){ return __uint_as_float(u & 0xffff0000u); }
__device__ __forceinline__ u16 f2bf(float f){
  uint32 u = __float_as_uint(f);
  u += 0x7fffu + ((u >> 16) & 1u);   // RNE
  return (u16)(u >> 16);
}

// ---------------- fp32 -> bf16 table conversion ----------------
__global__ void k_cvt(const float* __restrict__ x, u16* __restrict__ t, int n4){
  int g = blockIdx.x * 256 + threadIdx.x;
  int stride = gridDim.x * 256;
  for (int i = g; i < n4; i += stride){
    float4 v = ((const float4*)x)[i];
    ushort4 p;
    p.x = f2bf(v.x); p.y = f2bf(v.y); p.z = f2bf(v.z); p.w = f2bf(v.w);
    ((ushort4*)t)[i] = p;
  }
}

// ---------------- CSR build ----------------
__global__ void k_hist(const int* __restrict__ dst, int E, int* __restrict__ cnt){
  int i = blockIdx.x * 256 + threadIdx.x;
  if (i < E) atomicAdd(&cnt[dst[i]], 1);
}

__global__ void k_fill(const int* __restrict__ src, const int* __restrict__ dst, int E,
                       int* __restrict__ cur, int* __restrict__ csr){
  int i = blockIdx.x * 256 + threadIdx.x;
  if (i < E){
    int slot = atomicAdd(&cur[dst[i]], 1);
    csr[slot] = src[i];
  }
}

__global__ void k_chunk_sums(const int* c0, const int* c1, const int* c2, const int* c3,
                             int l0, int l1, int l2, int l3, int* __restrict__ sums){
  int a = blockIdx.y;
  const int* c = a==0?c0 : a==1?c1 : a==2?c2 : c3;
  int len     = a==0?l0 : a==1?l1 : a==2?l2 : l3;
  int base = blockIdx.x * 1024;
  if (base >= len) return;
  int t = threadIdx.x;
  int s = 0;
  #pragma unroll
  for (int u = 0; u < 4; ++u){ int i = base + t*4 + u; if (i < len) s += c[i]; }
  __shared__ int red[256];
  red[t] = s; __syncthreads();
  for (int o = 128; o > 0; o >>= 1){ if (t < o) red[t] += red[t+o]; __syncthreads(); }
  if (t == 0) sums[a*256 + blockIdx.x] = red[0];
}

__global__ void k_scan_sums(int* sums, int n0, int n1, int n2, int n3){
  int a = blockIdx.x;
  int n = a==0?n0 : a==1?n1 : a==2?n2 : n3;
  int t = threadIdx.x;
  __shared__ int shm[256];
  shm[t] = (t < n) ? sums[a*256 + t] : 0;
  __syncthreads();
  for (int o = 1; o < 256; o <<= 1){
    int x = shm[t];
    if (t >= o) x += shm[t-o];
    __syncthreads();
    shm[t] = x;
    __syncthreads();
  }
  sums[a*256 + t] = t ? shm[t-1] : 0;
}

__global__ void k_write_offsets(const int* c0, const int* c1, const int* c2, const int* c3,
                                int* o0, int* o1, int* o2, int* o3,
                                int* u0, int* u1, int* u2, int* u3,
                                int l0, int l1, int l2, int l3,
                                const int* __restrict__ sums){
  int a = blockIdx.y;
  const int* c = a==0?c0 : a==1?c1 : a==2?c2 : c3;
  int* off     = a==0?o0 : a==1?o1 : a==2?o2 : o3;
  int* cur     = a==0?u0 : a==1?u1 : a==2?u2 : u3;
  int len      = a==0?l0 : a==1?l1 : a==2?l2 : l3;
  int base = blockIdx.x * 1024;
  if (base >= len) return;
  int t = threadIdx.x;
  int v[4]; int s = 0;
  #pragma unroll
  for (int u = 0; u < 4; ++u){ int i = base + t*4 + u; v[u] = (i < len) ? c[i] : 0; s += v[u]; }
  __shared__ int shm[256];
  shm[t] = s; __syncthreads();
  for (int o = 1; o < 256; o <<= 1){
    int x = shm[t];
    if (t >= o) x += shm[t-o];
    __syncthreads();
    shm[t] = x;
    __syncthreads();
  }
  int run = (t ? shm[t-1] : 0) + sums[a*256 + blockIdx.x];
  #pragma unroll
  for (int u = 0; u < 4; ++u){
    int i = base + t*4 + u;
    if (i < len){
      off[i] = run; cur[i] = run; run += v[u];
      if (i == len - 1) off[len] = run;
    }
  }
}

// ---------------- weight concat (bf16, transposed: Wt[which][c][k]) ----------------
__global__ void k_prep(const float* __restrict__ Wl, const float* __restrict__ bl,
                       const float* __restrict__ Wr, u16* __restrict__ wt,
                       float* __restrict__ bcat){
  int g = blockIdx.x * 256 + threadIdx.x;
  const int NW = 4 * 128 * 384;
  if (g < NW){
    int which = g / 49152;          // blk*2 + side
    int blk = which >> 1, side = which & 1;
    int idx = g % 49152;
    int c = idx / 384;              // out col 0..127
    int k = idx % 384;              // 0..383
    int part = k >> 7, kk = k & 127;
    int tA = side == 0 ? 0 : 1;
    int tB = side == 0 ? 2 : 3;
    float v;
    if (part == 0)      v = 0.5f * Wl[(((blk*4 + tA)*128 + c)*128) + kk];
    else if (part == 1) v = 0.5f * Wl[(((blk*4 + tB)*128 + c)*128) + kk];
    else v = 0.5f * (Wr[(((blk*4 + tA)*128 + c)*128) + kk] + Wr[(((blk*4 + tB)*128 + c)*128) + kk]);
    wt[g] = f2bf(v);
  } else if (g < NW + 512){
    int i = g - NW;
    int which = i >> 7;
    int blk = which >> 1, side = which & 1;
    int c = i & 127;
    int tA = side == 0 ? 0 : 1;
    int tB = side == 0 ? 2 : 3;
    bcat[which*128 + c] = 0.5f * (bl[(blk*4 + tA)*128 + c] + bl[(blk*4 + tB)*128 + c]);
  }
}

// ---------------- fused gather-mean + MFMA GEMM ----------------
// 32 rows x 128 cols per block; A staged as bf16 in LDS (one barrier), matmul
// via mfma_f32_16x16x32_bf16 with B read straight from L2-resident Wt[c][k].
__global__ __launch_bounds__(256, 6) void k_gemm(
    int M,
    const int* __restrict__ off0, const int* __restrict__ csr0, const u16* __restrict__ tab0,
    const float* __restrict__ sc0, const float* __restrict__ sh0,
    const int* __restrict__ off1, const int* __restrict__ csr1, const u16* __restrict__ tab1,
    const float* __restrict__ sc1, const float* __restrict__ sh1,
    const u16* __restrict__ tabd, const float* __restrict__ scd, const float* __restrict__ shd,
    const u16* __restrict__ Wt, const float* __restrict__ bias,
    float* __restrict__ out32, u16* __restrict__ out16)
{
  __shared__ u16 As[32][392];     // 392 = 384 + 8 pad -> 16B-unit stride 49 (odd): 2-way max
  const int tid = threadIdx.x;
  const int row0 = blockIdx.x * 32;
  const int lane = tid & 63;
  const int wave = tid >> 6;

  // ---- stage A = [mean_gather(p0) | mean_gather(p1) | self(p2)] as bf16 ----
  for (int part = 0; part < 3; ++part){
    const int* off; const int* csr; const u16* tab; const float* sc; const float* sh;
    if (part == 0){ off = off0; csr = csr0; tab = tab0; sc = sc0; sh = sh0; }
    else if (part == 1){ off = off1; csr = csr1; tab = tab1; sc = sc1; sh = sh1; }
    else { off = nullptr; csr = nullptr; tab = tabd; sc = scd; sh = shd; }
    const bool bn = (sc != nullptr);
    float scx = 1.f, scy = 1.f, shx = 0.f, shy = 0.f;
    if (bn){
      scx = sc[2*lane]; scy = sc[2*lane+1];
      shx = sh[2*lane]; shy = sh[2*lane+1];
    }

    for (int rr = 0; rr < 8; ++rr){
      int r = (wave << 3) + rr;
      int row = row0 + r;                 // wave-uniform
      float vx = 0.f, vy = 0.f;
      if (row < M){
        if (part < 2){
          int s = off[row], e = off[row+1];
          int n = e - s;
          float ux = 0.f, uy = 0.f;
          for (int base = s; base < e; base += 64){
            int rem = e - base; if (rem > 64) rem = 64;
            int vidx = 0;
            if (base + lane < e) vidx = csr[base + lane];   // all indices in 1 load
            int i = 0;
            if (bn){
              for (; i + 4 <= rem; i += 4){
                int s0 = __shfl(vidx, i),   s1 = __shfl(vidx, i+1);
                int s2 = __shfl(vidx, i+2), s3 = __shfl(vidx, i+3);
                uint32 x0 = *(const uint32*)(tab + (size_t)s0*FH + 2*lane);
                uint32 x1 = *(const uint32*)(tab + (size_t)s1*FH + 2*lane);
                uint32 x2 = *(const uint32*)(tab + (size_t)s2*FH + 2*lane);
                uint32 x3 = *(const uint32*)(tab + (size_t)s3*FH + 2*lane);
                vx += lrelu(fmaf(bfl(x0), scx, shx)); vy += lrelu(fmaf(bfh(x0), scy, shy));
                ux += lrelu(fmaf(bfl(x1), scx, shx)); uy += lrelu(fmaf(bfh(x1), scy, shy));
                vx += lrelu(fmaf(bfl(x2), scx, shx)); vy += lrelu(fmaf(bfh(x2), scy, shy));
                ux += lrelu(fmaf(bfl(x3), scx, shx)); uy += lrelu(fmaf(bfh(x3), scy, shy));
              }
              for (; i < rem; ++i){
                int s0 = __shfl(vidx, i);
                uint32 x0 = *(const uint32*)(tab + (size_t)s0*FH + 2*lane);
                vx += lrelu(fmaf(bfl(x0), scx, shx)); vy += lrelu(fmaf(bfh(x0), scy, shy));
              }
            } else {
              for (; i + 4 <= rem; i += 4){
                int s0 = __shfl(vidx, i),   s1 = __shfl(vidx, i+1);
                int s2 = __shfl(vidx, i+2), s3 = __shfl(vidx, i+3);
                uint32 x0 = *(const uint32*)(tab + (size_t)s0*FH + 2*lane);
                uint32 x1 = *(const uint32*)(tab + (size_t)s1*FH + 2*lane);
                uint32 x2 = *(const uint32*)(tab + (size_t)s2*FH + 2*lane);
                uint32 x3 = *(const uint32*)(tab + (size_t)s3*FH + 2*lane);
                vx += bfl(x0); vy += bfh(x0);
                ux += bfl(x1); uy += bfh(x1);
                vx += bfl(x2); vy += bfh(x2);
                ux += bfl(x3); uy += bfh(x3);
              }
              for (; i < rem; ++i){
                int s0 = __shfl(vidx, i);
                uint32 x0 = *(const uint32*)(tab + (size_t)s0*FH + 2*lane);
                vx += bfl(x0); vy += bfh(x0);
              }
            }
          }
          float inv = 1.f / (float)(n > 1 ? n : 1);
          vx = (vx + ux) * inv;
          vy = (vy + uy) * inv;
        } else {
          uint32 x = *(const uint32*)(tabd + (size_t)row*FH + 2*lane);
          float fx = bfl(x), fy = bfh(x);
          if (bn){
            vx = lrelu(fmaf(fx, scx, shx));
            vy = lrelu(fmaf(fy, scy, shy));
          } else { vx = fx; vy = fy; }
        }
      }
      uint32 pk = ((uint32)f2bf(vy) << 16) | (uint32)f2bf(vx);
      *(uint32*)&As[r][part*128 + 2*lane] = pk;
    }
  }
  __syncthreads();

  // ---- MFMA: wave = 16 rows x 64 cols; K = 384 ----
  const int rowtile = wave >> 1;      // 0..1
  const int colhalf = wave & 1;       // 0..1
  const int qm  = lane & 15;
  const int quad = lane >> 4;
  f32x4 acc[4] = {{0,0,0,0},{0,0,0,0},{0,0,0,0},{0,0,0,0}};
  const u16* abase = &As[rowtile*16 + qm][quad*8];
  const u16* wbase = Wt + ((size_t)(colhalf*64 + qm) * 384 + quad*8);

  #pragma unroll
  for (int k0 = 0; k0 < 384; k0 += 32){
    bf16x8 a  = *(const bf16x8*)(abase + k0);
    bf16x8 b0 = *(const bf16x8*)(wbase + 0*16*384 + k0);
    bf16x8 b1 = *(const bf16x8*)(wbase + 1*16*384 + k0);
    bf16x8 b2 = *(const bf16x8*)(wbase + 2*16*384 + k0);
    bf16x8 b3 = *(const bf16x8*)(wbase + 3*16*384 + k0);
    acc[0] = __builtin_amdgcn_mfma_f32_16x16x32_bf16(a, b0, acc[0], 0, 0, 0);
    acc[1] = __builtin_amdgcn_mfma_f32_16x16x32_bf16(a, b1, acc[1], 0, 0, 0);
    acc[2] = __builtin_amdgcn_mfma_f32_16x16x32_bf16(a, b2, acc[2], 0, 0, 0);
    acc[3] = __builtin_amdgcn_mfma_f32_16x16x32_bf16(a, b3, acc[3], 0, 0, 0);
  }

  // ---- epilogue: D[m=quad*4+reg][n=qm] ----
  #pragma unroll
  for (int f = 0; f < 4; ++f){
    int col = colhalf*64 + f*16 + qm;
    float bi = bias[col];
    #pragma unroll
    for (int reg = 0; reg < 4; ++reg){
      int row = row0 + rowtile*16 + quad*4 + reg;
      if (row < M){
        float o = acc[f][reg] + bi;
        if (out32) out32[(size_t)row*FH + col] = o;
        if (out16) out16[(size_t)row*FH + col] = f2bf(o);
      }
    }
  }
}

// ---------------- BN ----------------
__global__ void k_bn_stats(const float* __restrict__ x, int M,
                           float* __restrict__ gsum, float* __restrict__ gsq){
  int t = threadIdx.x;
  int f = t & 127;
  int half = t >> 7;
  float s = 0.f, q = 0.f;
  for (int row = blockIdx.x*2 + half; row < M; row += gridDim.x*2){
    float v = x[(size_t)row*FH + f];
    s += v; q += v*v;
  }
  __shared__ float red[256];
  red[t] = s; __syncthreads();
  if (t < 128) atomicAdd(&gsum[t], red[t] + red[t+128]);
  __syncthreads();
  red[t] = q; __syncthreads();
  if (t < 128) atomicAdd(&gsq[t], red[t] + red[t+128]);
}

__global__ void k_bn_stats16(const u16* __restrict__ x, int M,
                             float* __restrict__ gsum, float* __restrict__ gsq){
  int t = threadIdx.x;
  int f = t & 127;
  int half = t >> 7;
  float s = 0.f, q = 0.f;
  for (int row = blockIdx.x*2 + half; row < M; row += gridDim.x*2){
    float v = __uint_as_float(((uint32)x[(size_t)row*FH + f]) << 16);
    s += v; q += v*v;
  }
  __shared__ float red[256];
  red[t] = s; __syncthreads();
  if (t < 128) atomicAdd(&gsum[t], red[t] + red[t+128]);
  __syncthreads();
  red[t] = q; __syncthreads();
  if (t < 128) atomicAdd(&gsq[t], red[t] + red[t+128]);
}

__global__ void k_bn_finalize(const float* __restrict__ sF, const float* __restrict__ qF, float invMF,
                              const float* __restrict__ sH, const float* __restrict__ qH, float invMH,
                              const float* __restrict__ gamma, const float* __restrict__ beta,
                              float* scF, float* shF, float* scH, float* shH){
  int t = threadIdx.x;
  if (t < 128){
    float mu = sF[t] * invMF;
    float var = qF[t] * invMF - mu*mu;
    float s = gamma[t] * rsqrtf(var + BNEPS);
    scF[t] = s; shF[t] = beta[t] - mu*s;
  } else {
    int f = t - 128;
    float mu = sH[f] * invMH;
    float var = qH[f] * invMH - mu*mu;
    float s = gamma[f] * rsqrtf(var + BNEPS);
    scH[f] = s; shH[f] = beta[f] - mu*s;
  }
}

__global__ void k_apply(float* __restrict__ x, int n4,
                        const float* __restrict__ sc, const float* __restrict__ shf){
  int g = blockIdx.x * blockDim.x + threadIdx.x;
  int stride = gridDim.x * blockDim.x;
  for (int i = g; i < n4; i += stride){
    float4 v = ((const float4*)x)[i];
    int f = (i*4) & 127;
    float4 s = *(const float4*)(sc + f);
    float4 b = *(const float4*)(shf + f);
    v.x = lrelu(fmaf(v.x, s.x, b.x));
    v.y = lrelu(fmaf(v.y, s.y, b.y));
    v.z = lrelu(fmaf(v.z, s.z, b.z));
    v.w = lrelu(fmaf(v.w, s.w, b.w));
    ((float4*)x)[i] = v;
  }
}

// ---------------- launch ----------------
extern "C" void kernel_launch(void* const* d_in, const int* in_sizes, int n_in,
                              void* d_out, int out_size, void* d_ws, size_t ws_size,
                              hipStream_t stream) {
  const float* x_host = (const float*)d_in[0];
  const float* x_flow = (const float*)d_in[1];
  const int* ei_s  = (const int*)d_in[2];
  const int* ei_rv = (const int*)d_in[3];
  const int* ei_p  = (const int*)d_in[4];
  const int* ei_rc = (const int*)d_in[5];
  const float* Wl    = (const float*)d_in[6];
  const float* bl    = (const float*)d_in[7];
  const float* Wr    = (const float*)d_in[8];
  const float* gamma = (const float*)d_in[9];
  const float* beta  = (const float*)d_in[10];

  const int NH = in_sizes[0] / FH;   // 50000
  const int NF = in_sizes[1] / FH;   // 200000
  const int Es  = in_sizes[2] / 2;
  const int Erv = in_sizes[3] / 2;
  const int Ep  = in_sizes[4] / 2;
  const int Erc = in_sizes[5] / 2;

  float* out_h = (float*)d_out;
  float* out_f = (float*)d_out + (size_t)NH * FH;

  char* p = (char*)d_ws;
  auto alloc = [&](size_t bytes) -> void* {
    void* r = (void*)p;
    p += (bytes + 255) & ~(size_t)255;
    return r;
  };
  u16* xf16  = (u16*)alloc((size_t)NF * FH * 2);  // bf16 input tables
  u16* xh16  = (u16*)alloc((size_t)NH * FH * 2);
  u16* f16_0 = (u16*)alloc((size_t)NF * FH * 2);  // block-0 raw outputs (bf16)
  u16* h16_0 = (u16*)alloc((size_t)NH * FH * 2);
  u16* wcat  = (u16*)alloc((size_t)4 * 49152 * 2); // bf16 Wt[which][c][k]
  float* bcat   = (float*)alloc(512 * 4);
  float* stats  = (float*)alloc(1024 * 4);
  float* ssbuf  = (float*)alloc(1024 * 4);
  int* cnt_s = (int*)alloc((size_t)NF * 4);
  int* cnt_p = (int*)alloc((size_t)NF * 4);
  int* cnt_r = (int*)alloc((size_t)NH * 4);
  int* cnt_q = (int*)alloc((size_t)NH * 4);
  int* off_s = (int*)alloc((size_t)(NF+1) * 4);
  int* off_p = (int*)alloc((size_t)(NF+1) * 4);
  int* off_r = (int*)alloc((size_t)(NH+1) * 4);
  int* off_q = (int*)alloc((size_t)(NH+1) * 4);
  int* cur_s = (int*)alloc((size_t)NF * 4);
  int* cur_p = (int*)alloc((size_t)NF * 4);
  int* cur_r = (int*)alloc((size_t)NH * 4);
  int* cur_q = (int*)alloc((size_t)NH * 4);
  int* csr_s = (int*)alloc((size_t)Es * 4);
  int* csr_p = (int*)alloc((size_t)Ep * 4);
  int* csr_r = (int*)alloc((size_t)Erv * 4);
  int* csr_q = (int*)alloc((size_t)Erc * 4);
  int* ssum  = (int*)alloc(1024 * 4);

  size_t cnt_bytes = (char*)cnt_q + (size_t)NH*4 - (char*)cnt_s;
  hipMemsetAsync(cnt_s, 0, cnt_bytes, stream);
  hipMemsetAsync(stats, 0, 1024 * 4, stream);

  k_prep<<<(4*128*384 + 512 + 255)/256, 256, 0, stream>>>(Wl, bl, Wr, wcat, bcat);
  k_cvt<<<1024, 256, 0, stream>>>(x_flow, xf16, NF * FH / 4);
  k_cvt<<<1024, 256, 0, stream>>>(x_host, xh16, NH * FH / 4);

  k_hist<<<(Es +255)/256, 256, 0, stream>>>(ei_s  + Es,  Es,  cnt_s);
  k_hist<<<(Ep +255)/256, 256, 0, stream>>>(ei_p  + Ep,  Ep,  cnt_p);
  k_hist<<<(Erv+255)/256, 256, 0, stream>>>(ei_rv + Erv, Erv, cnt_r);
  k_hist<<<(Erc+255)/256, 256, 0, stream>>>(ei_rc + Erc, Erc, cnt_q);

  int nchF = (NF + 1023) / 1024;   // 196
  int nchH = (NH + 1023) / 1024;   // 49
  dim3 gscan(nchF, 4);
  k_chunk_sums<<<gscan, 256, 0, stream>>>(cnt_s, cnt_p, cnt_r, cnt_q, NF, NF, NH, NH, ssum);
  k_scan_sums<<<4, 256, 0, stream>>>(ssum, nchF, nchF, nchH, nchH);
  k_write_offsets<<<gscan, 256, 0, stream>>>(cnt_s, cnt_p, cnt_r, cnt_q,
                                             off_s, off_p, off_r, off_q,
                                             cur_s, cur_p, cur_r, cur_q,
                                             NF, NF, NH, NH, ssum);

  k_fill<<<(Es +255)/256, 256, 0, stream>>>(ei_s,  ei_s  + Es,  Es,  cur_s, csr_s);
  k_fill<<<(Ep +255)/256, 256, 0, stream>>>(ei_p,  ei_p  + Ep,  Ep,  cur_p, csr_p);
  k_fill<<<(Erv+255)/256, 256, 0, stream>>>(ei_rv, ei_rv + Erv, Erv, cur_r, csr_r);
  k_fill<<<(Erc+255)/256, 256, 0, stream>>>(ei_rc, ei_rc + Erc, Erc, cur_q, csr_q);

  int gF = (NF + 31) / 32;   // 6250
  int gH = (NH + 31) / 32;   // 1563

  for (int blk = 0; blk < 2; ++blk){
    const u16* fcur = blk ? f16_0 : xf16;
    const u16* hcur = blk ? h16_0 : xh16;
    const float* scF = blk ? ssbuf + 0   : nullptr;
    const float* shF = blk ? ssbuf + 128 : nullptr;
    const float* scH = blk ? ssbuf + 256 : nullptr;
    const float* shH = blk ? ssbuf + 384 : nullptr;
    float* oF32 = blk ? out_f : nullptr;
    float* oH32 = blk ? out_h : nullptr;
    u16*   oF16 = blk ? nullptr : f16_0;
    u16*   oH16 = blk ? nullptr : h16_0;
    const u16* wf = wcat + (size_t)(blk*2 + 0) * 49152;
    const u16* wh = wcat + (size_t)(blk*2 + 1) * 49152;
    const float* bf = bcat + (blk*2 + 0) * 128;
    const float* bh = bcat + (blk*2 + 1) * 128;

    k_gemm<<<gF, 256, 0, stream>>>(NF,
        off_s, csr_s, hcur, scH, shH,
        off_p, csr_p, fcur, scF, shF,
        fcur, scF, shF,
        wf, bf, oF32, oF16);
    k_gemm<<<gH, 256, 0, stream>>>(NH,
        off_r, csr_r, fcur, scF, shF,
        off_q, csr_q, fcur, scF, shF,
        hcur, scH, shH,
        wh, bh, oH32, oH16);

    float* st = stats + blk * 512;
    if (blk == 0){
      k_bn_stats16<<<512, 256, 0, stream>>>(f16_0, NF, st + 0,   st + 128);
      k_bn_stats16<<<512, 256, 0, stream>>>(h16_0, NH, st + 256, st + 384);
    } else {
      k_bn_stats<<<512, 256, 0, stream>>>(out_f, NF, st + 0,   st + 128);
      k_bn_stats<<<512, 256, 0, stream>>>(out_h, NH, st + 256, st + 384);
    }
    float* ss = ssbuf + blk * 512;
    k_bn_finalize<<<1, 256, 0, stream>>>(st + 0, st + 128, 1.f/(float)NF,
                                         st + 256, st + 384, 1.f/(float)NH,
                                         gamma + blk*128, beta + blk*128,
                                         ss + 0, ss + 128, ss + 256, ss + 384);
  }

  k_apply<<<2048, 256, 0, stream>>>(out_f, NF * FH / 4, ssbuf + 512 + 0,   ssbuf + 512 + 128);
  k_apply<<<2048, 256, 0, stream>>>(out_h, NH * FH / 4, ssbuf + 512 + 256, ssbuf + 512 + 384);
}